// Round 1
// baseline (307.577 us; speedup 1.0000x reference)
//
#include <hip/hip_runtime.h>
#include <math.h>

#define B 64
#define N 2000
#define R 64
#define EMBED 512
#define LABELS 20

// ws layout (floats):
//  [0]      A   = <theta_w, phi_w>
//  [1]      C2  = <theta_b, phi_w>
//  [2+b]    fmax[b]
//  [66+b]   fmin[b]
//  [256 ..] GfMixed[B][N]  (Gf, overwritten in-place by mixed)
//  [256 + B*N ..] hidden[EMBED][B]
#define SC_OFF 0
#define GF_OFF 256
#define HID_OFF (256 + B * N)

// ---------------- kernel 1: scalars + per-batch max/min ----------------
__global__ void prep_kernel(const float* __restrict__ f,
                            const float* __restrict__ tw,
                            const float* __restrict__ tb,
                            const float* __restrict__ pw,
                            const float* __restrict__ pb,
                            float* __restrict__ sc) {
    int bid = blockIdx.x;
    if (bid == B) {
        int t = threadIdx.x;
        if (t < R) {
            float a = tw[t] * pw[t];
            float c = tb[t] * pw[t];
            for (int off = 32; off > 0; off >>= 1) {
                a += __shfl_down(a, off);
                c += __shfl_down(c, off);
            }
            if (t == 0) { sc[0] = a; sc[1] = c; }
        }
        return;
    }
    int b = bid;
    const float* fb = f + b * N;
    float mx = -1e30f, mn = 1e30f;
    for (int i = threadIdx.x; i < N; i += 256) {
        float v = fb[i];
        mx = fmaxf(mx, v);
        mn = fminf(mn, v);
    }
    __shared__ float smx[256], smn[256];
    smx[threadIdx.x] = mx;
    smn[threadIdx.x] = mn;
    __syncthreads();
    for (int s = 128; s > 0; s >>= 1) {
        if (threadIdx.x < s) {
            smx[threadIdx.x] = fmaxf(smx[threadIdx.x], smx[threadIdx.x + s]);
            smn[threadIdx.x] = fminf(smn[threadIdx.x], smn[threadIdx.x + s]);
        }
        __syncthreads();
    }
    if (threadIdx.x == 0) {
        sc[2 + b] = smx[0];
        sc[66 + b] = smn[0];
    }
}

// ---------------- kernel 2: Gf[b][n] = sum_m G[n][m] * f[b][m] ----------------
// block = 256 threads = 4 waves; wave handles one row n, lanes = b.
__global__ void gf_kernel(const float* __restrict__ G,
                          const float* __restrict__ f,
                          float* __restrict__ Gf) {
    int wv = threadIdx.x >> 6;
    int lane = threadIdx.x & 63;      // b
    int n = blockIdx.x * 4 + wv;      // < 2000 exactly (500 blocks)
    const float4* Gr = (const float4*)(G + (size_t)n * N);
    const float4* fr = (const float4*)(f + (size_t)lane * N);
    float acc = 0.f;
    for (int i = 0; i < N / 4; ++i) {
        float4 g = Gr[i];
        float4 v = fr[i];
        acc = fmaf(g.x, v.x, acc);
        acc = fmaf(g.y, v.y, acc);
        acc = fmaf(g.z, v.z, acc);
        acc = fmaf(g.w, v.w, acc);
    }
    Gf[(size_t)lane * N + n] = acc;
}

// ---------------- kernel 3: softmax-weighted sum + relu + residual ----------------
// grid 512 blocks: b = bid>>3, chunk = bid&7; thread -> n = chunk*256 + tid.
__global__ void main_kernel(const float* __restrict__ f,
                            const float* __restrict__ sc,
                            float* __restrict__ GfMixed) {
    __shared__ float fb[N];
    int b = blockIdx.x >> 3;
    int chunk = blockIdx.x & 7;
    const float4* frow = (const float4*)(f + (size_t)b * N);
    for (int i = threadIdx.x; i < N / 4; i += 256) {
        ((float4*)fb)[i] = frow[i];
    }
    __syncthreads();
    int n = chunk * 256 + threadIdx.x;
    if (n >= N) return;

    float A = sc[0], C2 = sc[1];
    float fmaxb = sc[2 + b], fminb = sc[66 + b];
    float fn = fb[n];
    float t = fmaf(A, fn, C2);
    float mx = (t >= 0.f) ? t * fmaxb : t * fminb;
    const float L2E = 1.4426950408889634f;
    float t2 = t * L2E;
    float nmx2 = -mx * L2E;
    float Z = 0.f, W = 0.f;
    for (int i = 0; i < N / 4; ++i) {
        float4 v = ((const float4*)fb)[i];   // LDS broadcast (uniform addr)
        float e0 = exp2f(fmaf(v.x, t2, nmx2));
        float e1 = exp2f(fmaf(v.y, t2, nmx2));
        float e2 = exp2f(fmaf(v.z, t2, nmx2));
        float e3 = exp2f(fmaf(v.w, t2, nmx2));
        Z += e0 + e1 + e2 + e3;
        W = fmaf(e0, v.x, W);
        W = fmaf(e1, v.y, W);
        W = fmaf(e2, v.z, W);
        W = fmaf(e3, v.w, W);
    }
    size_t idx = (size_t)b * N + n;
    float r = GfMixed[idx] + W / Z;
    r = fmaxf(r, 0.f);
    GfMixed[idx] = r + fn;   // mixed, in-place
}

// ---------------- kernel 4: hidden[e][b] = tanh(mixed[b,:] . fc1_w[e,:] + fc1_b[e]) ----------------
// block per e; 4 waves split m; lanes = b.
__global__ void fc1_kernel(const float* __restrict__ mixed,
                           const float* __restrict__ w1,
                           const float* __restrict__ b1,
                           float* __restrict__ hidden) {
    int e = blockIdx.x;
    int wv = threadIdx.x >> 6;
    int lane = threadIdx.x & 63;   // b
    const float4* wr = (const float4*)(w1 + (size_t)e * N) + wv * 125;
    const float4* mr = (const float4*)(mixed + (size_t)lane * N) + wv * 125;
    float acc = 0.f;
    for (int i = 0; i < 125; ++i) {
        float4 g = wr[i];
        float4 v = mr[i];
        acc = fmaf(g.x, v.x, acc);
        acc = fmaf(g.y, v.y, acc);
        acc = fmaf(g.z, v.z, acc);
        acc = fmaf(g.w, v.w, acc);
    }
    __shared__ float part[4][64];
    part[wv][lane] = acc;
    __syncthreads();
    if (threadIdx.x < 64) {
        float s = part[0][lane] + part[1][lane] + part[2][lane] + part[3][lane];
        hidden[(size_t)e * B + lane] = tanhf(s + b1[e]);
    }
}

// ---------------- kernel 5: logits[b][l] = hidden[:,b] . fc2_w[l,:] + fc2_b[l] ----------------
__global__ void fc2_kernel(const float* __restrict__ hidden,
                           const float* __restrict__ w2,
                           const float* __restrict__ b2,
                           float* __restrict__ out) {
    int l = blockIdx.x;
    int wv = threadIdx.x >> 6;
    int lane = threadIdx.x & 63;   // b
    float acc = 0.f;
    for (int e = wv * 128; e < wv * 128 + 128; ++e) {
        acc = fmaf(w2[(size_t)l * EMBED + e], hidden[(size_t)e * B + lane], acc);
    }
    __shared__ float part[4][64];
    part[wv][lane] = acc;
    __syncthreads();
    if (threadIdx.x < 64) {
        out[(size_t)lane * LABELS + l] =
            part[0][lane] + part[1][lane] + part[2][lane] + part[3][lane] + b2[l];
    }
}

extern "C" void kernel_launch(void* const* d_in, const int* in_sizes, int n_in,
                              void* d_out, int out_size, void* d_ws, size_t ws_size,
                              hipStream_t stream) {
    const float* feature = (const float*)d_in[0];
    const float* init_graph = (const float*)d_in[1];
    const float* theta_w = (const float*)d_in[2];
    const float* theta_b = (const float*)d_in[3];
    const float* phi_w = (const float*)d_in[4];
    const float* phi_b = (const float*)d_in[5];
    const float* fc1_w = (const float*)d_in[6];
    const float* fc1_b = (const float*)d_in[7];
    const float* fc2_w = (const float*)d_in[8];
    const float* fc2_b = (const float*)d_in[9];
    float* out = (float*)d_out;

    float* ws = (float*)d_ws;
    float* sc = ws + SC_OFF;
    float* GfMixed = ws + GF_OFF;
    float* hidden = ws + HID_OFF;

    hipLaunchKernelGGL(prep_kernel, dim3(B + 1), dim3(256), 0, stream,
                       feature, theta_w, theta_b, phi_w, phi_b, sc);
    hipLaunchKernelGGL(gf_kernel, dim3(N / 4), dim3(256), 0, stream,
                       init_graph, feature, GfMixed);
    hipLaunchKernelGGL(main_kernel, dim3(B * 8), dim3(256), 0, stream,
                       feature, sc, GfMixed);
    hipLaunchKernelGGL(fc1_kernel, dim3(EMBED), dim3(256), 0, stream,
                       GfMixed, fc1_w, fc1_b, hidden);
    hipLaunchKernelGGL(fc2_kernel, dim3(LABELS), dim3(256), 0, stream,
                       hidden, fc2_w, fc2_b, out);
}

// Round 2
// 253.016 us; speedup vs baseline: 1.2156x; 1.2156x over previous
//
#include <hip/hip_runtime.h>
#include <math.h>

#define B 64
#define N 2000
#define R 64
#define EMBED 512
#define LABELS 20

// ws layout (floats):
//  [0]      A   = <theta_w, phi_w>
//  [1]      C2  = <theta_b, phi_w>
//  [2+b]    fmax[b]
//  [66+b]   fmin[b]
//  [256]                GfMixT[N][B]   (GfT, overwritten in-place by mixedT)
//  [256 + N*B]          fT[N][B]       (transposed feature)
//  [256 + 2*N*B]        hidden[EMBED][B]
#define SC_OFF 0
#define GF_OFF 256
#define FT_OFF (256 + N * B)
#define HID_OFF (256 + 2 * N * B)

// ---------------- kernel 1: scalars + per-batch max/min ----------------
__global__ void prep_kernel(const float* __restrict__ f,
                            const float* __restrict__ tw,
                            const float* __restrict__ tb,
                            const float* __restrict__ pw,
                            const float* __restrict__ pb,
                            float* __restrict__ sc) {
    int bid = blockIdx.x;
    if (bid == B) {
        int t = threadIdx.x;
        if (t < R) {
            float a = tw[t] * pw[t];
            float c = tb[t] * pw[t];
            for (int off = 32; off > 0; off >>= 1) {
                a += __shfl_down(a, off);
                c += __shfl_down(c, off);
            }
            if (t == 0) { sc[0] = a; sc[1] = c; }
        }
        return;
    }
    int b = bid;
    const float* fb = f + b * N;
    float mx = -1e30f, mn = 1e30f;
    for (int i = threadIdx.x; i < N; i += 256) {
        float v = fb[i];
        mx = fmaxf(mx, v);
        mn = fminf(mn, v);
    }
    __shared__ float smx[256], smn[256];
    smx[threadIdx.x] = mx;
    smn[threadIdx.x] = mn;
    __syncthreads();
    for (int s = 128; s > 0; s >>= 1) {
        if (threadIdx.x < s) {
            smx[threadIdx.x] = fmaxf(smx[threadIdx.x], smx[threadIdx.x + s]);
            smn[threadIdx.x] = fminf(smn[threadIdx.x], smn[threadIdx.x + s]);
        }
        __syncthreads();
    }
    if (threadIdx.x == 0) {
        sc[2 + b] = smx[0];
        sc[66 + b] = smn[0];
    }
}

// ---------------- kernel 1b: fT[m][b] = f[b][m] (64x64 LDS tile transpose) ----------------
__global__ void transpose_kernel(const float* __restrict__ f,
                                 float* __restrict__ fT) {
    __shared__ float tile[64][65];
    int m0 = blockIdx.x * 64;
    int lane = threadIdx.x & 63;
    int w = threadIdx.x >> 6;
    for (int bb = w; bb < 64; bb += 4) {
        tile[lane][bb] = (m0 + lane < N) ? f[(size_t)bb * N + m0 + lane] : 0.f;
    }
    __syncthreads();
    for (int mm = w; mm < 64; mm += 4) {
        if (m0 + mm < N) fT[(size_t)(m0 + mm) * B + lane] = tile[mm][lane];
    }
}

// ---------------- kernel 2: GfT[n][b] = sum_m G[n][m] * fT[m][b] ----------------
// 500 blocks x 256. Block handles 4 n's; wave w does m-quarter w for all 4 n;
// lanes = b. G loads wave-uniform float4 (1 line), fT loads lane-coalesced.
__global__ void gf2_kernel(const float* __restrict__ G,
                           const float* __restrict__ fT,
                           float* __restrict__ GfT) {
    int lane = threadIdx.x & 63;
    int w = threadIdx.x >> 6;
    int n0 = blockIdx.x * 4;
    int mstart = w * (N / 4);   // 500

    const float4* G0 = (const float4*)(G + (size_t)(n0 + 0) * N + mstart);
    const float4* G1 = (const float4*)(G + (size_t)(n0 + 1) * N + mstart);
    const float4* G2 = (const float4*)(G + (size_t)(n0 + 2) * N + mstart);
    const float4* G3 = (const float4*)(G + (size_t)(n0 + 3) * N + mstart);
    const float* ft = fT + (size_t)mstart * B + lane;

    float acc0 = 0.f, acc1 = 0.f, acc2 = 0.f, acc3 = 0.f;
#pragma unroll 2
    for (int i = 0; i < (N / 4) / 4; ++i) {   // 125 iters of 4 m's
        float4 g0 = G0[i];
        float4 g1 = G1[i];
        float4 g2 = G2[i];
        float4 g3 = G3[i];
        float f0 = ft[(4 * i + 0) * B];
        float f1 = ft[(4 * i + 1) * B];
        float f2 = ft[(4 * i + 2) * B];
        float f3 = ft[(4 * i + 3) * B];
        acc0 = fmaf(g0.x, f0, acc0); acc0 = fmaf(g0.y, f1, acc0);
        acc0 = fmaf(g0.z, f2, acc0); acc0 = fmaf(g0.w, f3, acc0);
        acc1 = fmaf(g1.x, f0, acc1); acc1 = fmaf(g1.y, f1, acc1);
        acc1 = fmaf(g1.z, f2, acc1); acc1 = fmaf(g1.w, f3, acc1);
        acc2 = fmaf(g2.x, f0, acc2); acc2 = fmaf(g2.y, f1, acc2);
        acc2 = fmaf(g2.z, f2, acc2); acc2 = fmaf(g2.w, f3, acc2);
        acc3 = fmaf(g3.x, f0, acc3); acc3 = fmaf(g3.y, f1, acc3);
        acc3 = fmaf(g3.z, f2, acc3); acc3 = fmaf(g3.w, f3, acc3);
    }
    __shared__ float part[4][4][64];
    part[w][0][lane] = acc0;
    part[w][1][lane] = acc1;
    part[w][2][lane] = acc2;
    part[w][3][lane] = acc3;
    __syncthreads();
    // wave w finishes n0+w
    float s = part[0][w][lane] + part[1][w][lane] + part[2][w][lane] + part[3][w][lane];
    GfT[(size_t)(n0 + w) * B + lane] = s;
}

// ---------------- kernel 3: softmax-weighted sum + relu + residual ----------------
// grid 512 blocks: b = bid>>3, chunk = bid&7; thread -> n = chunk*256 + tid.
// Reads/writes GfMixT[n][b] (one scattered access each — cheap).
__global__ void main_kernel(const float* __restrict__ f,
                            const float* __restrict__ sc,
                            float* __restrict__ GfMixT) {
    __shared__ float fb[N];
    int b = blockIdx.x >> 3;
    int chunk = blockIdx.x & 7;
    const float4* frow = (const float4*)(f + (size_t)b * N);
    for (int i = threadIdx.x; i < N / 4; i += 256) {
        ((float4*)fb)[i] = frow[i];
    }
    __syncthreads();
    int n = chunk * 256 + threadIdx.x;
    if (n >= N) return;

    float A = sc[0], C2 = sc[1];
    float fmaxb = sc[2 + b], fminb = sc[66 + b];
    float fn = fb[n];
    float t = fmaf(A, fn, C2);
    float mx = (t >= 0.f) ? t * fmaxb : t * fminb;
    const float L2E = 1.4426950408889634f;
    float t2 = t * L2E;
    float nmx2 = -mx * L2E;
    float Z = 0.f, W = 0.f;
    for (int i = 0; i < N / 4; ++i) {
        float4 v = ((const float4*)fb)[i];   // LDS broadcast (uniform addr)
        float e0 = exp2f(fmaf(v.x, t2, nmx2));
        float e1 = exp2f(fmaf(v.y, t2, nmx2));
        float e2 = exp2f(fmaf(v.z, t2, nmx2));
        float e3 = exp2f(fmaf(v.w, t2, nmx2));
        Z += e0 + e1 + e2 + e3;
        W = fmaf(e0, v.x, W);
        W = fmaf(e1, v.y, W);
        W = fmaf(e2, v.z, W);
        W = fmaf(e3, v.w, W);
    }
    size_t idx = (size_t)n * B + b;
    float r = GfMixT[idx] + W / Z;
    r = fmaxf(r, 0.f);
    GfMixT[idx] = r + fn;   // mixedT, in-place
}

// ---------------- kernel 4: hidden[e][b] = tanh(sum_m mixT[m][b]*w1[e][m] + b1[e]) ----------------
// 128 blocks x 256. Block handles 4 e's; wave w does m-quarter w for all 4 e; lanes = b.
__global__ void fc1_kernel(const float* __restrict__ mixT,
                           const float* __restrict__ w1,
                           const float* __restrict__ b1,
                           float* __restrict__ hidden) {
    int lane = threadIdx.x & 63;
    int w = threadIdx.x >> 6;
    int e0 = blockIdx.x * 4;
    int mstart = w * (N / 4);

    const float4* W0 = (const float4*)(w1 + (size_t)(e0 + 0) * N + mstart);
    const float4* W1 = (const float4*)(w1 + (size_t)(e0 + 1) * N + mstart);
    const float4* W2 = (const float4*)(w1 + (size_t)(e0 + 2) * N + mstart);
    const float4* W3 = (const float4*)(w1 + (size_t)(e0 + 3) * N + mstart);
    const float* mt = mixT + (size_t)mstart * B + lane;

    float acc0 = 0.f, acc1 = 0.f, acc2 = 0.f, acc3 = 0.f;
#pragma unroll 2
    for (int i = 0; i < (N / 4) / 4; ++i) {
        float4 g0 = W0[i];
        float4 g1 = W1[i];
        float4 g2 = W2[i];
        float4 g3 = W3[i];
        float f0 = mt[(4 * i + 0) * B];
        float f1 = mt[(4 * i + 1) * B];
        float f2 = mt[(4 * i + 2) * B];
        float f3 = mt[(4 * i + 3) * B];
        acc0 = fmaf(g0.x, f0, acc0); acc0 = fmaf(g0.y, f1, acc0);
        acc0 = fmaf(g0.z, f2, acc0); acc0 = fmaf(g0.w, f3, acc0);
        acc1 = fmaf(g1.x, f0, acc1); acc1 = fmaf(g1.y, f1, acc1);
        acc1 = fmaf(g1.z, f2, acc1); acc1 = fmaf(g1.w, f3, acc1);
        acc2 = fmaf(g2.x, f0, acc2); acc2 = fmaf(g2.y, f1, acc2);
        acc2 = fmaf(g2.z, f2, acc2); acc2 = fmaf(g2.w, f3, acc2);
        acc3 = fmaf(g3.x, f0, acc3); acc3 = fmaf(g3.y, f1, acc3);
        acc3 = fmaf(g3.z, f2, acc3); acc3 = fmaf(g3.w, f3, acc3);
    }
    __shared__ float part[4][4][64];
    part[w][0][lane] = acc0;
    part[w][1][lane] = acc1;
    part[w][2][lane] = acc2;
    part[w][3][lane] = acc3;
    __syncthreads();
    float s = part[0][w][lane] + part[1][w][lane] + part[2][w][lane] + part[3][w][lane];
    hidden[(size_t)(e0 + w) * B + lane] = tanhf(s + b1[e0 + w]);
}

// ---------------- kernel 5: logits[b][l] = hidden[:,b] . fc2_w[l,:] + fc2_b[l] ----------------
__global__ void fc2_kernel(const float* __restrict__ hidden,
                           const float* __restrict__ w2,
                           const float* __restrict__ b2,
                           float* __restrict__ out) {
    int l = blockIdx.x;
    int wv = threadIdx.x >> 6;
    int lane = threadIdx.x & 63;   // b
    float acc = 0.f;
    for (int e = wv * 128; e < wv * 128 + 128; ++e) {
        acc = fmaf(w2[(size_t)l * EMBED + e], hidden[(size_t)e * B + lane], acc);
    }
    __shared__ float part[4][64];
    part[wv][lane] = acc;
    __syncthreads();
    if (threadIdx.x < 64) {
        out[(size_t)lane * LABELS + l] =
            part[0][lane] + part[1][lane] + part[2][lane] + part[3][lane] + b2[l];
    }
}

extern "C" void kernel_launch(void* const* d_in, const int* in_sizes, int n_in,
                              void* d_out, int out_size, void* d_ws, size_t ws_size,
                              hipStream_t stream) {
    const float* feature = (const float*)d_in[0];
    const float* init_graph = (const float*)d_in[1];
    const float* theta_w = (const float*)d_in[2];
    const float* theta_b = (const float*)d_in[3];
    const float* phi_w = (const float*)d_in[4];
    const float* phi_b = (const float*)d_in[5];
    const float* fc1_w = (const float*)d_in[6];
    const float* fc1_b = (const float*)d_in[7];
    const float* fc2_w = (const float*)d_in[8];
    const float* fc2_b = (const float*)d_in[9];
    float* out = (float*)d_out;

    float* ws = (float*)d_ws;
    float* sc = ws + SC_OFF;
    float* GfMixT = ws + GF_OFF;
    float* fT = ws + FT_OFF;
    float* hidden = ws + HID_OFF;

    hipLaunchKernelGGL(prep_kernel, dim3(B + 1), dim3(256), 0, stream,
                       feature, theta_w, theta_b, phi_w, phi_b, sc);
    hipLaunchKernelGGL(transpose_kernel, dim3((N + 63) / 64), dim3(256), 0, stream,
                       feature, fT);
    hipLaunchKernelGGL(gf2_kernel, dim3(N / 4), dim3(256), 0, stream,
                       init_graph, fT, GfMixT);
    hipLaunchKernelGGL(main_kernel, dim3(B * 8), dim3(256), 0, stream,
                       feature, sc, GfMixT);
    hipLaunchKernelGGL(fc1_kernel, dim3(EMBED / 4), dim3(256), 0, stream,
                       GfMixT, fc1_w, fc1_b, hidden);
    hipLaunchKernelGGL(fc2_kernel, dim3(LABELS), dim3(256), 0, stream,
                       hidden, fc2_w, fc2_b, out);
}

// Round 3
// 223.304 us; speedup vs baseline: 1.3774x; 1.1331x over previous
//
#include <hip/hip_runtime.h>
#include <math.h>

#define B 64
#define N 2000
#define R 64
#define EMBED 512
#define LABELS 20

#define NM 23   // moments S_0..S_22 (per batch)
#define NK 22   // exp-series terms k=0..21:  e^x = sum_k x^k/k!

// ws layout (floats):
//  [0..1]    A = <theta_w,phi_w>, C2 = <theta_b,phi_w>
//  [64..]    S[NM][B]   power sums S_k[b] = sum_m f[b][m]^k
//  [2048..]  fT[N][B]
//  [2048+N*B..]   mixT[N][B]
//  [2048+2*N*B..] hidden[EMBED][B]
#define SC_OFF 0
#define S_OFF 64
#define FT_OFF 2048
#define MIX_OFF (FT_OFF + N * B)
#define HID_OFF (MIX_OFF + N * B)

__constant__ float c_invfact[NK] = {
    1.0f, 1.0f, 0.5f,
    1.6666666666666666e-01f, 4.1666666666666664e-02f, 8.3333333333333332e-03f,
    1.3888888888888889e-03f, 1.9841269841269841e-04f, 2.4801587301587302e-05f,
    2.7557319223985893e-06f, 2.7557319223985894e-07f, 2.5052108385441720e-08f,
    2.0876756987868100e-09f, 1.6059043836821616e-10f, 1.1470745597729726e-11f,
    7.6471637318198170e-13f, 4.7794773323873860e-14f, 2.8114572543455206e-15f,
    1.5619206968586225e-16f, 8.2206352466243300e-18f, 4.1103176233121650e-19f,
    1.9572941063391263e-20f,
};

// ---------------- kernel 1: A, C2 + per-batch power sums (f64 accum) ----------------
// grid = B+1 blocks x 64 threads (1 wave). Blocks 0..63: moments for batch b.
// Block B: A = <tw,pw>, C2 = <tb,pw>.
__global__ __launch_bounds__(64) void prep_kernel(const float* __restrict__ f,
                                                  const float* __restrict__ tw,
                                                  const float* __restrict__ tb,
                                                  const float* __restrict__ pw,
                                                  const float* __restrict__ pb,
                                                  float* __restrict__ sc,
                                                  float* __restrict__ S) {
    int bid = blockIdx.x;
    int lane = threadIdx.x;
    if (bid == B) {
        float a = tw[lane] * pw[lane];
        float c = tb[lane] * pw[lane];
        for (int off = 32; off; off >>= 1) {
            a += __shfl_down(a, off);
            c += __shfl_down(c, off);
        }
        if (lane == 0) { sc[0] = a; sc[1] = c; }
        return;
    }
    const float* fb = f + (size_t)bid * N;
    double acc[NM];
#pragma unroll
    for (int k = 0; k < NM; ++k) acc[k] = 0.0;
    for (int m = lane; m < N; m += 64) {
        double x = (double)fb[m];
        double p = 1.0;
#pragma unroll
        for (int k = 0; k < NM; ++k) { acc[k] += p; p *= x; }
    }
    for (int off = 32; off; off >>= 1) {
#pragma unroll
        for (int k = 0; k < NM; ++k) acc[k] += __shfl_down(acc[k], off);
    }
    if (lane == 0) {
#pragma unroll
        for (int k = 0; k < NM; ++k) S[k * 64 + bid] = (float)acc[k];
    }
}

// ---------------- kernel 2: fT[m][b] = f[b][m] (64x64 LDS tile transpose) ----------------
__global__ __launch_bounds__(256) void transpose_kernel(const float* __restrict__ f,
                                                        float* __restrict__ fT) {
    __shared__ float tile[64][65];
    int m0 = blockIdx.x * 64;
    int lane = threadIdx.x & 63;
    int w = threadIdx.x >> 6;
    for (int bb = w; bb < 64; bb += 4) {
        tile[lane][bb] = (m0 + lane < N) ? f[(size_t)bb * N + m0 + lane] : 0.f;
    }
    __syncthreads();
    for (int mm = w; mm < 64; mm += 4) {
        if (m0 + mm < N) fT[(size_t)(m0 + mm) * B + lane] = tile[mm][lane];
    }
}

// ---------------- kernel 3: Gf + softmax-poly + relu + residual, fused ----------------
// mixT[n][b] = relu( sum_m G[n][m] fT[m][b]  +  W(t)/Z(t) ) + f[b][n]
// where t = A*f[b][n] + C2,  Z = sum_k t^k/k! S_k[b],  W = sum_k t^k/k! S_{k+1}[b].
// grid 250 blocks x 512 threads (8 waves). Block: 8 n-rows; wave w owns n0+w, lanes = b.
// G rows staged into LDS coalesced, double-buffered (issue-early/write-late).
#define CH 500
__global__ __launch_bounds__(512) void gf3_kernel(const float* __restrict__ G,
                                                  const float* __restrict__ fT,
                                                  const float* __restrict__ sc,
                                                  const float* __restrict__ S,
                                                  float* __restrict__ mixT) {
    __shared__ float Gs[2][8][CH];   // 32 KB
    int tid = threadIdx.x;
    int lane = tid & 63;     // b
    int w = tid >> 6;        // 0..7
    int n0 = blockIdx.x * 8;

    // stage chunk 0
    for (int j = tid; j < 1000; j += 512) {
        int row = j / 125, col = j - row * 125;
        ((float4*)&Gs[0][row][0])[col] =
            ((const float4*)(G + (size_t)(n0 + row) * N))[col];
    }
    __syncthreads();

    float a0 = 0.f, a1 = 0.f, a2 = 0.f, a3 = 0.f;
    for (int ch = 0; ch < 4; ++ch) {
        // issue next-chunk loads early (latency hides under compute)
        float4 r0, r1;
        int j1 = tid + 512;
        int row0 = tid / 125, col0 = tid - row0 * 125;
        int row1 = j1 / 125, col1 = j1 - row1 * 125;
        if (ch < 3) {
            r0 = ((const float4*)(G + (size_t)(n0 + row0) * N + (ch + 1) * CH))[col0];
            if (j1 < 1000)
                r1 = ((const float4*)(G + (size_t)(n0 + row1) * N + (ch + 1) * CH))[col1];
        }
        // compute current chunk
        const float* ftp = fT + (size_t)ch * CH * B + lane;
        const float4* gs = (const float4*)&Gs[ch & 1][w][0];
#pragma unroll 4
        for (int i = 0; i < CH / 4; ++i) {
            float4 g = gs[i];
            float f0 = ftp[(4 * i + 0) * B];
            float f1 = ftp[(4 * i + 1) * B];
            float f2 = ftp[(4 * i + 2) * B];
            float f3 = ftp[(4 * i + 3) * B];
            a0 = fmaf(g.x, f0, a0);
            a1 = fmaf(g.y, f1, a1);
            a2 = fmaf(g.z, f2, a2);
            a3 = fmaf(g.w, f3, a3);
        }
        // write staged regs into the other buffer
        if (ch < 3) {
            ((float4*)&Gs[(ch + 1) & 1][row0][0])[col0] = r0;
            if (j1 < 1000)
                ((float4*)&Gs[(ch + 1) & 1][row1][0])[col1] = r1;
        }
        __syncthreads();
    }

    float gf = (a0 + a1) + (a2 + a3);
    int n = n0 + w;
    float fn = fT[(size_t)n * B + lane];
    float A = sc[0], C2 = sc[1];
    float t = fmaf(A, fn, C2);
    float Z = 0.f, Wv = 0.f, tp = 1.f;
#pragma unroll
    for (int k = 0; k < NK; ++k) {
        float c = tp * c_invfact[k];
        Z = fmaf(c, S[k * 64 + lane], Z);
        Wv = fmaf(c, S[(k + 1) * 64 + lane], Wv);
        tp *= t;
    }
    float r = fmaxf(gf + Wv / Z, 0.f);
    mixT[(size_t)n * B + lane] = r + fn;
}

// ---------------- kernel 4: hidden[e][b] = tanh(sum_m mixT[m][b]*w1[e][m] + b1[e]) ----------------
// 256 blocks x 256. Block: 2 e's; wave w does m-quarter w for both; lanes = b.
__global__ __launch_bounds__(256) void fc1_kernel(const float* __restrict__ mixT,
                                                  const float* __restrict__ w1,
                                                  const float* __restrict__ b1,
                                                  float* __restrict__ hidden) {
    int tid = threadIdx.x;
    int lane = tid & 63;
    int w = tid >> 6;
    int e0 = blockIdx.x * 2;
    int mstart = w * (N / 4);   // 500
    const float4* W0 = (const float4*)(w1 + (size_t)e0 * N + mstart);
    const float4* W1 = (const float4*)(w1 + (size_t)(e0 + 1) * N + mstart);
    const float* mt = mixT + (size_t)mstart * B + lane;
    float p0 = 0.f, p1 = 0.f, q0 = 0.f, q1 = 0.f;
#pragma unroll 2
    for (int i = 0; i < 125; ++i) {
        float4 g0 = W0[i];
        float4 g1 = W1[i];
        float f0 = mt[(4 * i + 0) * B];
        float f1 = mt[(4 * i + 1) * B];
        float f2 = mt[(4 * i + 2) * B];
        float f3 = mt[(4 * i + 3) * B];
        p0 = fmaf(g0.x, f0, p0); p0 = fmaf(g0.y, f1, p0);
        q0 = fmaf(g0.z, f2, q0); q0 = fmaf(g0.w, f3, q0);
        p1 = fmaf(g1.x, f0, p1); p1 = fmaf(g1.y, f1, p1);
        q1 = fmaf(g1.z, f2, q1); q1 = fmaf(g1.w, f3, q1);
    }
    __shared__ float part[4][2][64];
    part[w][0][lane] = p0 + q0;
    part[w][1][lane] = p1 + q1;
    __syncthreads();
    if (w < 2) {
        float s = part[0][w][lane] + part[1][w][lane] +
                  part[2][w][lane] + part[3][w][lane];
        hidden[(size_t)(e0 + w) * B + lane] = tanhf(s + b1[e0 + w]);
    }
}

// ---------------- kernel 5: logits[b][l] ----------------
__global__ __launch_bounds__(256) void fc2_kernel(const float* __restrict__ hidden,
                                                  const float* __restrict__ w2,
                                                  const float* __restrict__ b2,
                                                  float* __restrict__ out) {
    int l = blockIdx.x;
    int tid = threadIdx.x;
    int lane = tid & 63;
    int w = tid >> 6;
    const float4* W = (const float4*)(w2 + (size_t)l * EMBED) + w * 32;
    const float* h = hidden + (size_t)(w * 128) * B + lane;
    float a0 = 0.f, a1 = 0.f, a2 = 0.f, a3 = 0.f;
#pragma unroll 4
    for (int i = 0; i < 32; ++i) {
        float4 g = W[i];
        a0 = fmaf(g.x, h[(4 * i + 0) * B], a0);
        a1 = fmaf(g.y, h[(4 * i + 1) * B], a1);
        a2 = fmaf(g.z, h[(4 * i + 2) * B], a2);
        a3 = fmaf(g.w, h[(4 * i + 3) * B], a3);
    }
    __shared__ float part[4][64];
    part[w][lane] = (a0 + a1) + (a2 + a3);
    __syncthreads();
    if (w == 0) {
        out[(size_t)lane * LABELS + l] =
            part[0][lane] + part[1][lane] + part[2][lane] + part[3][lane] + b2[l];
    }
}

extern "C" void kernel_launch(void* const* d_in, const int* in_sizes, int n_in,
                              void* d_out, int out_size, void* d_ws, size_t ws_size,
                              hipStream_t stream) {
    const float* feature = (const float*)d_in[0];
    const float* init_graph = (const float*)d_in[1];
    const float* theta_w = (const float*)d_in[2];
    const float* theta_b = (const float*)d_in[3];
    const float* phi_w = (const float*)d_in[4];
    const float* phi_b = (const float*)d_in[5];
    const float* fc1_w = (const float*)d_in[6];
    const float* fc1_b = (const float*)d_in[7];
    const float* fc2_w = (const float*)d_in[8];
    const float* fc2_b = (const float*)d_in[9];
    float* out = (float*)d_out;

    float* ws = (float*)d_ws;
    float* sc = ws + SC_OFF;
    float* S = ws + S_OFF;
    float* fT = ws + FT_OFF;
    float* mixT = ws + MIX_OFF;
    float* hidden = ws + HID_OFF;

    hipLaunchKernelGGL(prep_kernel, dim3(B + 1), dim3(64), 0, stream,
                       feature, theta_w, theta_b, phi_w, phi_b, sc, S);
    hipLaunchKernelGGL(transpose_kernel, dim3((N + 63) / 64), dim3(256), 0, stream,
                       feature, fT);
    hipLaunchKernelGGL(gf3_kernel, dim3(N / 8), dim3(512), 0, stream,
                       init_graph, fT, sc, S, mixT);
    hipLaunchKernelGGL(fc1_kernel, dim3(EMBED / 2), dim3(256), 0, stream,
                       mixT, fc1_w, fc1_b, hidden);
    hipLaunchKernelGGL(fc2_kernel, dim3(LABELS), dim3(256), 0, stream,
                       hidden, fc2_w, fc2_b, out);
}

// Round 4
// 129.338 us; speedup vs baseline: 2.3781x; 1.7265x over previous
//
#include <hip/hip_runtime.h>
#include <math.h>

#define B 64
#define N 2000
#define R 64
#define EMBED 512
#define LABELS 20

#define NM 23   // moments S_0..S_22 per batch
#define NK 22   // exp-series terms

#define KS_GF 8
#define KC_GF 256
#define KS_FC 16
#define KC_FC 128

// ws layout (floats):
#define SC_OFF 0                         // 2 scalars (A, C2)
#define S_OFF 64                         // S[NM][64]
#define MIX_OFF 2048                     // mixT[N][64]
#define HID_OFF (MIX_OFF + N * B)        // hidden[EMBED][64]
#define PGF_OFF (HID_OFF + EMBED * B)    // Pgf[KS_GF][N][64]   (4.1 MB)
#define PFC_OFF (PGF_OFF + KS_GF * N * B) // Pfc[KS_FC][EMBED][64] (2.1 MB)
// total ~6.9 MB

__constant__ float c_invfact[NK] = {
    1.0f, 1.0f, 0.5f,
    1.6666666666666666e-01f, 4.1666666666666664e-02f, 8.3333333333333332e-03f,
    1.3888888888888889e-03f, 1.9841269841269841e-04f, 2.4801587301587302e-05f,
    2.7557319223985893e-06f, 2.7557319223985894e-07f, 2.5052108385441720e-08f,
    2.0876756987868100e-09f, 1.6059043836821616e-10f, 1.1470745597729726e-11f,
    7.6471637318198170e-13f, 4.7794773323873860e-14f, 2.8114572543455206e-15f,
    1.5619206968586225e-16f, 8.2206352466243300e-18f, 4.1103176233121650e-19f,
    1.9572941063391263e-20f,
};

// ---------------- kernel 1: scalars + per-batch power sums (f64) ----------------
// blocks 0..63: moments for batch b (256 threads); block 64: A, C2.
__global__ __launch_bounds__(256) void prep_kernel(const float* __restrict__ f,
                                                   const float* __restrict__ tw,
                                                   const float* __restrict__ tb,
                                                   const float* __restrict__ pw,
                                                   float* __restrict__ sc,
                                                   float* __restrict__ S) {
    int bid = blockIdx.x;
    int tid = threadIdx.x;
    if (bid == B) {
        if (tid < R) {
            float a = tw[tid] * pw[tid];
            float c = tb[tid] * pw[tid];
            for (int off = 32; off; off >>= 1) {
                a += __shfl_down(a, off);
                c += __shfl_down(c, off);
            }
            if (tid == 0) { sc[0] = a; sc[1] = c; }
        }
        return;
    }
    const float* fb = f + (size_t)bid * N;
    double acc[NM];
#pragma unroll
    for (int k = 0; k < NM; ++k) acc[k] = 0.0;
    for (int m = tid; m < N; m += 256) {
        double x = (double)fb[m];
        double p = 1.0;
#pragma unroll
        for (int k = 0; k < NM; ++k) { acc[k] += p; p *= x; }
    }
    for (int off = 32; off; off >>= 1) {
#pragma unroll
        for (int k = 0; k < NM; ++k) acc[k] += __shfl_down(acc[k], off);
    }
    __shared__ double sred[4][NM];
    int w = tid >> 6, lane = tid & 63;
    if (lane == 0) {
#pragma unroll
        for (int k = 0; k < NM; ++k) sred[w][k] = acc[k];
    }
    __syncthreads();
    if (tid < NM) {
        double s = sred[0][tid] + sred[1][tid] + sred[2][tid] + sred[3][tid];
        S[tid * 64 + bid] = (float)s;
    }
}

// ---------------- kernel 2: gf partial GEMM ----------------
// P[ks][n][b] = sum_{k in split ks} G[n][k] * f[b][k]
// grid 256 = 32 ntiles x 8 ksplits; 512 thr (8 waves); wave w -> 8 n-rows.
// LDS: Gs[64][256] f32 (64KB) + fs swizzled (64KB); dynamic 128 KB.
__global__ __launch_bounds__(512) void gf_partial(const float* __restrict__ G,
                                                  const float* __restrict__ f,
                                                  float* __restrict__ P) {
    extern __shared__ float lds[];
    float* Gs = lds;                  // [64][KC_GF]
    float* fs = lds + 64 * KC_GF;     // element (m,b) at dword m*64 + (b ^ ((m>>2)&31))
    int tid = threadIdx.x;
    int lane = tid & 63, w = tid >> 6;
    int nt = blockIdx.x & 31;
    int ks = blockIdx.x >> 5;
    int n0 = nt * 64, k0 = ks * KC_GF;

    // stage G tile 64 x 256 (coalesced; clamp row/col at edges — garbage x 0 is fine)
#pragma unroll
    for (int j = 0; j < 8; ++j) {
        int flat = tid * 4 + j * 2048;
        int r = flat >> 8, c = flat & 255;
        int n = n0 + r; if (n > N - 1) n = N - 1;
        int cc = c; if (k0 + c + 3 >= N) cc = N - 4 - k0;
        float4 g = *(const float4*)(G + (size_t)n * N + (k0 + cc));
        *(float4*)(Gs + r * KC_GF + c) = g;
    }
    // stage f -> fs (transpose during store, XOR-swizzled, zero-padded)
#pragma unroll
    for (int j = 0; j < 8; ++j) {
        int b = (tid >> 6) + j * 8;      // wave-uniform
        int c = (tid & 63) * 4;          // m = c..c+3, m>>2 == lane
        int kc = k0 + c;
        float4 v = make_float4(0.f, 0.f, 0.f, 0.f);
        if (kc + 3 < N) {
            v = *(const float4*)(f + (size_t)b * N + kc);
        } else {
            const float* fb = f + (size_t)b * N;
            if (kc < N) v.x = fb[kc];
            if (kc + 1 < N) v.y = fb[kc + 1];
            if (kc + 2 < N) v.z = fb[kc + 2];
        }
        float* p = fs + c * 64 + (b ^ (lane & 31));
        p[0] = v.x; p[64] = v.y; p[128] = v.z; p[192] = v.w;
    }
    __syncthreads();

    float acc[8];
#pragma unroll
    for (int r = 0; r < 8; ++r) acc[r] = 0.f;
    int nrow = w * 8;
    for (int i = 0; i < KC_GF / 4; ++i) {
        const float* fp = fs + i * 256 + (lane ^ (i & 31));
        float f0 = fp[0], f1 = fp[64], f2 = fp[128], f3 = fp[192];
#pragma unroll
        for (int r = 0; r < 8; ++r) {
            const float4 g = *(const float4*)(Gs + (nrow + r) * KC_GF + 4 * i);
            acc[r] = fmaf(g.x, f0, acc[r]);
            acc[r] = fmaf(g.y, f1, acc[r]);
            acc[r] = fmaf(g.z, f2, acc[r]);
            acc[r] = fmaf(g.w, f3, acc[r]);
        }
    }
    size_t base = ((size_t)ks * N + n0 + nrow) * 64 + lane;
#pragma unroll
    for (int r = 0; r < 8; ++r) {
        if (n0 + nrow + r < N) P[base + (size_t)r * 64] = acc[r];
    }
}

// ---------------- kernel 3: reduce gf partials + softmax-poly + relu + residual ----------------
__global__ __launch_bounds__(256) void reduce_gf(const float* __restrict__ P,
                                                 const float* __restrict__ f,
                                                 const float* __restrict__ sc,
                                                 const float* __restrict__ S,
                                                 float* __restrict__ mixT) {
    int flat = blockIdx.x * 256 + threadIdx.x;   // 0..127999
    int n = flat >> 6, b = flat & 63;
    float s = 0.f;
#pragma unroll
    for (int k = 0; k < KS_GF; ++k) s += P[(size_t)k * N * 64 + flat];
    float fn = f[(size_t)b * N + n];
    float A = sc[0], C2 = sc[1];
    float t = fmaf(A, fn, C2);
    float Z = 0.f, Wv = 0.f, tp = 1.f;
#pragma unroll
    for (int k = 0; k < NK; ++k) {
        float c = tp * c_invfact[k];
        Z = fmaf(c, S[k * 64 + b], Z);
        Wv = fmaf(c, S[(k + 1) * 64 + b], Wv);
        tp *= t;
    }
    float r = fmaxf(s + Wv / Z, 0.f);
    mixT[flat] = r + fn;
}

// ---------------- kernel 4: fc1 partial GEMM ----------------
// P[ks][e][b] = sum_{k in split} w1[e][k] * mixT[k][b]
// grid 256 = 16 etiles x 16 ksplits; 256 thr (4 waves); wave w -> 8 e-rows.
__global__ __launch_bounds__(256) void fc1_partial(const float* __restrict__ w1,
                                                   const float* __restrict__ mixT,
                                                   float* __restrict__ P) {
    __shared__ float Ws[32 * KC_FC];     // 16 KB
    __shared__ float ms[KC_FC * 65];     // 33.3 KB, pad-65
    int tid = threadIdx.x;
    int lane = tid & 63, w = tid >> 6;
    int et = blockIdx.x & 15;
    int ks = blockIdx.x >> 4;
    int e0 = et * 32, k0 = ks * KC_FC;

#pragma unroll
    for (int j = 0; j < 4; ++j) {
        int flat = tid * 4 + j * 1024;
        int r = flat >> 7, c = flat & 127;
        int cc = c; if (k0 + c + 3 >= N) cc = N - 4 - k0;
        float4 g = *(const float4*)(w1 + (size_t)(e0 + r) * N + (k0 + cc));
        *(float4*)(Ws + r * KC_FC + c) = g;
    }
#pragma unroll
    for (int j = 0; j < 8; ++j) {
        int flat = tid * 4 + j * 1024;
        int k = flat >> 6, b4 = flat & 63;
        float4 v = make_float4(0.f, 0.f, 0.f, 0.f);
        if (k0 + k < N) v = *(const float4*)(mixT + (size_t)(k0 + k) * 64 + b4);
        float* p = ms + k * 65 + b4;     // scalar stores: pad-65 keeps banks 2-way
        p[0] = v.x; p[1] = v.y; p[2] = v.z; p[3] = v.w;
    }
    __syncthreads();

    float acc[8];
#pragma unroll
    for (int r = 0; r < 8; ++r) acc[r] = 0.f;
    int erow = w * 8;
    for (int i = 0; i < KC_FC / 4; ++i) {
        const float* fp = ms + (4 * i) * 65 + lane;
        float f0 = fp[0], f1 = fp[65], f2 = fp[130], f3 = fp[195];
#pragma unroll
        for (int r = 0; r < 8; ++r) {
            const float4 g = *(const float4*)(Ws + (erow + r) * KC_FC + 4 * i);
            acc[r] = fmaf(g.x, f0, acc[r]);
            acc[r] = fmaf(g.y, f1, acc[r]);
            acc[r] = fmaf(g.z, f2, acc[r]);
            acc[r] = fmaf(g.w, f3, acc[r]);
        }
    }
    size_t base = ((size_t)ks * EMBED + e0 + erow) * 64 + lane;
#pragma unroll
    for (int r = 0; r < 8; ++r) P[base + (size_t)r * 64] = acc[r];
}

// ---------------- kernel 5: reduce fc1 partials + bias + tanh ----------------
__global__ __launch_bounds__(256) void reduce_fc1(const float* __restrict__ P,
                                                  const float* __restrict__ b1,
                                                  float* __restrict__ hidden) {
    int flat = blockIdx.x * 256 + threadIdx.x;   // 0..32767
    int e = flat >> 6;
    float s = 0.f;
#pragma unroll
    for (int k = 0; k < KS_FC; ++k) s += P[(size_t)k * EMBED * 64 + flat];
    hidden[flat] = tanhf(s + b1[e]);
}

// ---------------- kernel 6: logits ----------------
__global__ __launch_bounds__(256) void fc2_kernel(const float* __restrict__ hidden,
                                                  const float* __restrict__ w2,
                                                  const float* __restrict__ b2,
                                                  float* __restrict__ out) {
    int l = blockIdx.x;
    int tid = threadIdx.x;
    int lane = tid & 63;
    int w = tid >> 6;
    const float4* W = (const float4*)(w2 + (size_t)l * EMBED) + w * 32;
    const float* h = hidden + (size_t)(w * 128) * B + lane;
    float a0 = 0.f, a1 = 0.f, a2 = 0.f, a3 = 0.f;
#pragma unroll 4
    for (int i = 0; i < 32; ++i) {
        float4 g = W[i];
        a0 = fmaf(g.x, h[(4 * i + 0) * B], a0);
        a1 = fmaf(g.y, h[(4 * i + 1) * B], a1);
        a2 = fmaf(g.z, h[(4 * i + 2) * B], a2);
        a3 = fmaf(g.w, h[(4 * i + 3) * B], a3);
    }
    __shared__ float part[4][64];
    part[w][lane] = (a0 + a1) + (a2 + a3);
    __syncthreads();
    if (w == 0) {
        out[(size_t)lane * LABELS + l] =
            part[0][lane] + part[1][lane] + part[2][lane] + part[3][lane] + b2[l];
    }
}

extern "C" void kernel_launch(void* const* d_in, const int* in_sizes, int n_in,
                              void* d_out, int out_size, void* d_ws, size_t ws_size,
                              hipStream_t stream) {
    const float* feature = (const float*)d_in[0];
    const float* init_graph = (const float*)d_in[1];
    const float* theta_w = (const float*)d_in[2];
    const float* theta_b = (const float*)d_in[3];
    const float* phi_w = (const float*)d_in[4];
    const float* fc1_w = (const float*)d_in[6];
    const float* fc1_b = (const float*)d_in[7];
    const float* fc2_w = (const float*)d_in[8];
    const float* fc2_b = (const float*)d_in[9];
    float* out = (float*)d_out;

    float* ws = (float*)d_ws;
    float* sc = ws + SC_OFF;
    float* S = ws + S_OFF;
    float* mixT = ws + MIX_OFF;
    float* hidden = ws + HID_OFF;
    float* Pgf = ws + PGF_OFF;
    float* Pfc = ws + PFC_OFF;

    hipLaunchKernelGGL(prep_kernel, dim3(B + 1), dim3(256), 0, stream,
                       feature, theta_w, theta_b, phi_w, sc, S);
    hipLaunchKernelGGL(gf_partial, dim3(32 * KS_GF), dim3(512),
                       (64 * KC_GF + KC_GF * 64) * sizeof(float), stream,
                       init_graph, feature, Pgf);
    hipLaunchKernelGGL(reduce_gf, dim3(N * B / 256), dim3(256), 0, stream,
                       Pgf, feature, sc, S, mixT);
    hipLaunchKernelGGL(fc1_partial, dim3(16 * KS_FC), dim3(256), 0, stream,
                       fc1_w, mixT, Pfc);
    hipLaunchKernelGGL(reduce_fc1, dim3(EMBED * B / 256), dim3(256), 0, stream,
                       Pfc, fc1_b, hidden);
    hipLaunchKernelGGL(fc2_kernel, dim3(LABELS), dim3(256), 0, stream,
                       hidden, fc2_w, fc2_b, out);
}

// Round 6
// 125.056 us; speedup vs baseline: 2.4595x; 1.0342x over previous
//
#include <hip/hip_runtime.h>
#include <math.h>

#define B 64
#define N 2000
#define R 64
#define EMBED 512
#define LABELS 20

#define NM 23   // moments S_0..S_22 per batch
#define NK 22   // exp-series terms

#define KS 25   // k-splits
#define KC 80   // k-chunk (25*80 = 2000 exactly)
#define NT_GF 32
#define NT_FC 8

// ws layout (floats):
#define SC_OFF 0                         // A, C2
#define S_OFF 64                         // S[NM][64]
#define FT_OFF 2048                      // fT[N][64]
#define MIX_OFF (FT_OFF + N * B)         // mixT[N][64]
#define HID_OFF (MIX_OFF + N * B)        // hidden[EMBED][64]
#define PGF_OFF (HID_OFF + EMBED * B)    // Pgf[KS][N][64]    (12.8 MB)
#define PFC_OFF (PGF_OFF + KS * N * B)   // Pfc[KS][EMBED][64] (3.3 MB)

__constant__ float c_invfact[NK] = {
    1.0f, 1.0f, 0.5f,
    1.6666666666666666e-01f, 4.1666666666666664e-02f, 8.3333333333333332e-03f,
    1.3888888888888889e-03f, 1.9841269841269841e-04f, 2.4801587301587302e-05f,
    2.7557319223985893e-06f, 2.7557319223985894e-07f, 2.5052108385441720e-08f,
    2.0876756987868100e-09f, 1.6059043836821616e-10f, 1.1470745597729726e-11f,
    7.6471637318198170e-13f, 4.7794773323873860e-14f, 2.8114572543455206e-15f,
    1.5619206968586225e-16f, 8.2206352466243300e-18f, 4.1103176233121650e-19f,
    1.9572941063391263e-20f,
};

// ---------------- kernel 1 (fused): moments | scalars | transpose ----------------
// bid 0..63: per-batch power sums (f64). bid 64: A, C2. bid 65..96: fT tiles.
__global__ __launch_bounds__(256) void prep_fused(const float* __restrict__ f,
                                                  const float* __restrict__ tw,
                                                  const float* __restrict__ tb,
                                                  const float* __restrict__ pw,
                                                  float* __restrict__ sc,
                                                  float* __restrict__ S,
                                                  float* __restrict__ fT) {
    __shared__ float tile[64][65];
    __shared__ double sred[4][NM];
    int bid = blockIdx.x;
    int tid = threadIdx.x;
    if (bid >= 65) {
        int m0 = (bid - 65) * 64;
        int lane = tid & 63, w = tid >> 6;
        for (int bb = w; bb < 64; bb += 4)
            tile[lane][bb] = (m0 + lane < N) ? f[(size_t)bb * N + m0 + lane] : 0.f;
        __syncthreads();
        for (int mm = w; mm < 64; mm += 4)
            if (m0 + mm < N) fT[(size_t)(m0 + mm) * 64 + lane] = tile[mm][lane];
        return;
    }
    if (bid == 64) {
        if (tid < R) {
            float a = tw[tid] * pw[tid];
            float c = tb[tid] * pw[tid];
            for (int off = 32; off; off >>= 1) {
                a += __shfl_down(a, off);
                c += __shfl_down(c, off);
            }
            if (tid == 0) { sc[0] = a; sc[1] = c; }
        }
        return;
    }
    const float* fb = f + (size_t)bid * N;
    double acc[NM];
#pragma unroll
    for (int k = 0; k < NM; ++k) acc[k] = 0.0;
    for (int m = tid; m < N; m += 256) {
        double x = (double)fb[m];
        double p = 1.0;
#pragma unroll
        for (int k = 0; k < NM; ++k) { acc[k] += p; p *= x; }
    }
    for (int off = 32; off; off >>= 1) {
#pragma unroll
        for (int k = 0; k < NM; ++k) acc[k] += __shfl_down(acc[k], off);
    }
    int w = tid >> 6, lane = tid & 63;
    if (lane == 0) {
#pragma unroll
        for (int k = 0; k < NM; ++k) sred[w][k] = acc[k];
    }
    __syncthreads();
    if (tid < NM) {
        double s = sred[0][tid] + sred[1][tid] + sred[2][tid] + sred[3][tid];
        S[tid * 64 + bid] = (float)s;
    }
}

// ---------------- scalar-operand split-K GEMM ----------------
// P[ks][row][b] = sum_{k in chunk ks} A[row][k] * X[k][b]
// A row-major [M][N]; X k-major [N][64]. 512 thr = 8 waves; wave owns 8 rows.
// A values are wave-uniform -> SGPR s_loads; X slice lives in VGPRs (coalesced).
// No LDS, no barriers: inner loop is pure v_fmac with one SGPR operand.
template <int M>
__global__ __launch_bounds__(512) void gemm_part(const float* __restrict__ A,
                                                 const float* __restrict__ X,
                                                 float* __restrict__ P) {
    int tid = threadIdx.x;
    int lane = tid & 63;
    int w = __builtin_amdgcn_readfirstlane(tid >> 6);
    int ks = blockIdx.x % KS;
    int nt = blockIdx.x / KS;
    int k0 = ks * KC;
    int row0 = nt * 64 + w * 8;

    float vf[KC];
#pragma unroll
    for (int j = 0; j < KC; ++j) vf[j] = X[(size_t)(k0 + j) * 64 + lane];

    int rowc[8];
#pragma unroll
    for (int r = 0; r < 8; ++r) rowc[r] = (row0 + r < M) ? (row0 + r) : (M - 1);

    float acc[8];
#pragma unroll
    for (int r = 0; r < 8; ++r) acc[r] = 0.f;

#pragma unroll
    for (int j4 = 0; j4 < KC / 4; ++j4) {
#pragma unroll
        for (int r = 0; r < 8; ++r) {
            const float4 g = *(const float4*)(A + (size_t)rowc[r] * N + k0 + 4 * j4);
            acc[r] = fmaf(g.x, vf[4 * j4 + 0], acc[r]);
            acc[r] = fmaf(g.y, vf[4 * j4 + 1], acc[r]);
            acc[r] = fmaf(g.z, vf[4 * j4 + 2], acc[r]);
            acc[r] = fmaf(g.w, vf[4 * j4 + 3], acc[r]);
        }
    }
#pragma unroll
    for (int r = 0; r < 8; ++r) {
        int row = row0 + r;
        if (row < M) P[((size_t)ks * M + row) * 64 + lane] = acc[r];
    }
}

// ---------------- reduce gf partials + softmax-poly + relu + residual ----------------
__global__ __launch_bounds__(256) void reduce_gf(const float* __restrict__ P,
                                                 const float* __restrict__ fT,
                                                 const float* __restrict__ sc,
                                                 const float* __restrict__ S,
                                                 float* __restrict__ mixT) {
    int flat = blockIdx.x * 256 + threadIdx.x;   // 0..127999
    int b = flat & 63;
    float s = 0.f;
#pragma unroll
    for (int k = 0; k < KS; ++k) s += P[(size_t)k * N * 64 + flat];
    float fn = fT[flat];                         // fT[n][b], flat = n*64+b
    float A = sc[0], C2 = sc[1];
    float t = fmaf(A, fn, C2);
    float Z = 0.f, Wv = 0.f, tp = 1.f;
#pragma unroll
    for (int k = 0; k < NK; ++k) {
        float c = tp * c_invfact[k];
        Z = fmaf(c, S[k * 64 + b], Z);
        Wv = fmaf(c, S[(k + 1) * 64 + b], Wv);
        tp *= t;
    }
    float r = fmaxf(s + Wv / Z, 0.f);
    mixT[flat] = r + fn;
}

// ---------------- reduce fc1 partials + bias + tanh ----------------
__global__ __launch_bounds__(256) void reduce_fc1(const float* __restrict__ P,
                                                  const float* __restrict__ b1,
                                                  float* __restrict__ hidden) {
    int flat = blockIdx.x * 256 + threadIdx.x;   // 0..32767
    int e = flat >> 6;
    float s = 0.f;
#pragma unroll
    for (int k = 0; k < KS; ++k) s += P[(size_t)k * EMBED * 64 + flat];
    hidden[flat] = tanhf(s + b1[e]);
}

// ---------------- logits ----------------
__global__ __launch_bounds__(256) void fc2_kernel(const float* __restrict__ hidden,
                                                  const float* __restrict__ w2,
                                                  const float* __restrict__ b2,
                                                  float* __restrict__ out) {
    int l = blockIdx.x;
    int tid = threadIdx.x;
    int lane = tid & 63;
    int w = tid >> 6;
    const float4* W = (const float4*)(w2 + (size_t)l * EMBED) + w * 32;
    const float* h = hidden + (size_t)(w * 128) * B + lane;
    float a0 = 0.f, a1 = 0.f, a2 = 0.f, a3 = 0.f;
#pragma unroll 4
    for (int i = 0; i < 32; ++i) {
        float4 g = W[i];
        a0 = fmaf(g.x, h[(4 * i + 0) * B], a0);
        a1 = fmaf(g.y, h[(4 * i + 1) * B], a1);
        a2 = fmaf(g.z, h[(4 * i + 2) * B], a2);
        a3 = fmaf(g.w, h[(4 * i + 3) * B], a3);
    }
    __shared__ float part[4][64];
    part[w][lane] = (a0 + a1) + (a2 + a3);
    __syncthreads();
    if (w == 0) {
        out[(size_t)lane * LABELS + l] =
            part[0][lane] + part[1][lane] + part[2][lane] + part[3][lane] + b2[l];
    }
}

extern "C" void kernel_launch(void* const* d_in, const int* in_sizes, int n_in,
                              void* d_out, int out_size, void* d_ws, size_t ws_size,
                              hipStream_t stream) {
    const float* feature = (const float*)d_in[0];
    const float* init_graph = (const float*)d_in[1];
    const float* theta_w = (const float*)d_in[2];
    const float* theta_b = (const float*)d_in[3];
    const float* phi_w = (const float*)d_in[4];
    const float* fc1_w = (const float*)d_in[6];
    const float* fc1_b = (const float*)d_in[7];
    const float* fc2_w = (const float*)d_in[8];
    const float* fc2_b = (const float*)d_in[9];
    float* out = (float*)d_out;

    float* ws = (float*)d_ws;
    float* sc = ws + SC_OFF;
    float* S = ws + S_OFF;
    float* fT = ws + FT_OFF;
    float* mixT = ws + MIX_OFF;
    float* hidden = ws + HID_OFF;
    float* Pgf = ws + PGF_OFF;
    float* Pfc = ws + PFC_OFF;

    // moments + scalars + transpose, fused (97 blocks)
    hipLaunchKernelGGL(prep_fused, dim3(65 + (N + 63) / 64), dim3(256), 0, stream,
                       feature, theta_w, theta_b, phi_w, sc, S, fT);
    // gf: G[2000][2000] x fT -> Pgf
    hipLaunchKernelGGL((gemm_part<N>), dim3(NT_GF * KS), dim3(512), 0, stream,
                       init_graph, fT, Pgf);
    hipLaunchKernelGGL(reduce_gf, dim3(N * B / 256), dim3(256), 0, stream,
                       Pgf, fT, sc, S, mixT);
    // fc1: w1[512][2000] x mixT -> Pfc
    hipLaunchKernelGGL((gemm_part<EMBED>), dim3(NT_FC * KS), dim3(512), 0, stream,
                       fc1_w, mixT, Pfc);
    hipLaunchKernelGGL(reduce_fc1, dim3(EMBED * B / 256), dim3(256), 0, stream,
                       Pfc, fc1_b, hidden);
    hipLaunchKernelGGL(fc2_kernel, dim3(LABELS), dim3(256), 0, stream,
                       hidden, fc2_w, fc2_b, out);
}